// Round 11
// baseline (301.183 us; speedup 1.0000x reference)
//
#include <hip/hip_runtime.h>
#include <cstdint>
#include <cstddef>

// Problem constants (reference: B=4, N=2048, DIM=256, heads=8, groups=2)
#define B_    4
#define NPT   2048
#define DIM_  256
#define QKVW  768   // 3*DIM
#define XLEN  2097152   // 8192*256
#define QLEN  196608    // 768*256
#define PLEN  65536     // 256*256
#define TOTC  (XLEN + QLEN + 2 * PLEN)  // 2424832

typedef unsigned short ushort_t;
typedef short bf16x8 __attribute__((ext_vector_type(8)));
typedef float f32x4 __attribute__((ext_vector_type(4)));

// Fast gelu: A&S 7.1.26 erf (max abs err 1.5e-7).
__device__ __forceinline__ float gelu_fast(float x) {
  const float is2 = 0.70710678118654752440f;
  float z = x * is2;
  float az = __builtin_fabsf(z);
  float t = __builtin_amdgcn_rcpf(fmaf(0.3275911f, az, 1.0f));
  float p = fmaf(1.061405429f, t, -1.453152027f);
  p = fmaf(p, t, 1.421413741f);
  p = fmaf(p, t, -0.284496736f);
  p = fmaf(p, t, 0.254829592f);
  p = p * t;
  float e = __expf(-az * az);
  float er = fmaf(-p, e, 1.0f);
  er = __builtin_copysignf(er, x);
  return 0.5f * x * (1.0f + er);
}

// tanh-form gelu (~11 VALU; dev from erf-gelu ~1e-3 << 3.7e-2 threshold).
__device__ __forceinline__ float gelu_tanh(float x) {
  float x2 = x * x;
  float z2 = x * fmaf(0.0713548163f, x2, 1.5957691216f);
  float e = __expf(z2);
  float t = __builtin_amdgcn_rcpf(e + 1.0f);
  float th = fmaf(-2.0f, t, 1.0f);
  return 0.5f * x * (1.0f + th);
}

__device__ __forceinline__ ushort_t f2bf(float f) {
  unsigned u = __float_as_uint(f);
  unsigned r = (u + 0x7fffu + ((u >> 16) & 1u)) >> 16;
  return (ushort_t)r;
}
__device__ __forceinline__ float bf2f(ushort_t h) {
  return __uint_as_float(((unsigned)h) << 16);
}

template <int CTRL>
__device__ __forceinline__ void dppmin_step(int& lo, int& hi) {
  int olo = __builtin_amdgcn_update_dpp(lo, lo, CTRL, 0xf, 0xf, false);
  int ohi = __builtin_amdgcn_update_dpp(hi, hi, CTRL, 0xf, 0xf, false);
  unsigned long long o = ((unsigned long long)(unsigned)ohi << 32) | (unsigned)olo;
  unsigned long long c = ((unsigned long long)(unsigned)hi << 32) | (unsigned)lo;
  if (o < c) { lo = olo; hi = ohi; }
}
template <int CTRL>
__device__ __forceinline__ float dpp_addf(float x) {
  int s = __builtin_amdgcn_update_dpp(0, __float_as_int(x), CTRL, 0xf, 0xf, false);
  return x + __int_as_float(s);
}
// 32-lane sum within each half-wave: lane31 = sum(0..31), lane63 = sum(32..63)
__device__ __forceinline__ float head32_reduce(float u) {
  u = dpp_addf<0x111>(u);
  u = dpp_addf<0x112>(u);
  u = dpp_addf<0x114>(u);
  u = dpp_addf<0x118>(u);
  u = dpp_addf<0x142>(u);
  return u;
}

// ---------------------------------------------------------------------------
// PREP: fused KNN + convert (disjoint block ranges). Blocks 0..2047: KNN, one
// wave per query (DPP wave-min, packed u64 keys). Blocks 2048..4095: bf16
// convert (coalesced reads) + part zero.
// ---------------------------------------------------------------------------
__global__ __launch_bounds__(256) void prep_kernel(
    const float* __restrict__ pos, const float* __restrict__ x,
    const float* __restrict__ Wqkv, const float* __restrict__ Wproj,
    const float* __restrict__ Whead, int* __restrict__ idx_out,
    ushort_t* __restrict__ xbf, ushort_t* __restrict__ WqkvT,
    ushort_t* __restrict__ WprojT, ushort_t* __restrict__ WheadT,
    float* __restrict__ part) {
  int tid = threadIdx.x;
  if (blockIdx.x >= 2048) {
    int base = (blockIdx.x - 2048) * 256 + tid;
    if (base < 1024) part[base] = 0.f;
    for (int i = base; i < TOTC; i += 2048 * 256) {
      if (i < XLEN) {
        xbf[i] = f2bf(x[i]);
      } else if (i < XLEN + QLEN) {
        int e = i - XLEN;                  // input-major: coalesced read
        int k = e / 768, n = e - k * 768;
        WqkvT[n * 256 + k] = f2bf(Wqkv[e]);
      } else if (i < XLEN + QLEN + PLEN) {
        int e = i - XLEN - QLEN;
        int k = e >> 8, n = e & 255;
        WprojT[n * 256 + k] = f2bf(Wproj[e]);
      } else {
        int e = i - XLEN - QLEN - PLEN;
        int k = e >> 8, n = e & 255;
        WheadT[n * 256 + k] = f2bf(Whead[e]);
      }
    }
    return;
  }
  int wave = tid >> 6, lane = tid & 63;
  int wq = blockIdx.x * 4 + wave;
  int b = wq >> 11, n = wq & (NPT - 1);
  const float* pb = pos + (size_t)b * NPT * 3;
  float qx = pb[n * 3 + 0], qy = pb[n * 3 + 1], qz = pb[n * 3 + 2];
  unsigned long long keys[32];
  {
#pragma clang fp contract(off)
#pragma unroll
    for (int s = 0; s < 32; s++) {
      int j = lane + (s << 6);
      float dx = qx - pb[j * 3 + 0];
      float dy = qy - pb[j * 3 + 1];
      float dz = qz - pb[j * 3 + 2];
      float d = dx * dx;
      d = d + dy * dy;
      d = d + dz * dz;
      keys[s] = ((unsigned long long)__float_as_uint(d) << 32) | (unsigned int)j;
    }
  }
  unsigned long long gk[4];
#pragma unroll
  for (int gi = 0; gi < 4; gi++) {
    unsigned long long m = keys[gi * 8];
#pragma unroll
    for (int s = 1; s < 8; s++) {
      unsigned long long c = keys[gi * 8 + s];
      m = (c < m) ? c : m;
    }
    gk[gi] = m;
  }
  unsigned long long lkey = gk[0];
#pragma unroll
  for (int gi = 1; gi < 4; gi++) lkey = (gk[gi] < lkey) ? gk[gi] : lkey;
  int* outp = idx_out + (size_t)wq * 32;
  for (int r = 0; r < 32; r++) {
    int lo = (int)(unsigned)(lkey & 0xffffffffULL);
    int hi = (int)(unsigned)(lkey >> 32);
    dppmin_step<0x111>(lo, hi);
    dppmin_step<0x112>(lo, hi);
    dppmin_step<0x114>(lo, hi);
    dppmin_step<0x118>(lo, hi);
    dppmin_step<0x142>(lo, hi);
    dppmin_step<0x143>(lo, hi);
    unsigned int glo = (unsigned int)__builtin_amdgcn_readlane(lo, 63);
    unsigned int ghi = (unsigned int)__builtin_amdgcn_readlane(hi, 63);
    unsigned long long g = ((unsigned long long)ghi << 32) | glo;
    if (lkey == g) {
      outp[r] = (int)glo;
#pragma unroll
      for (int gi = 0; gi < 4; gi++) {
        if (gk[gi] == g) {
          unsigned long long m = ~0ULL;
#pragma unroll
          for (int s = 0; s < 8; s++) {
            unsigned long long c = keys[gi * 8 + s];
            if (c == g) { c = ~0ULL; keys[gi * 8 + s] = c; }
            m = (c < m) ? c : m;
          }
          gk[gi] = m;
        }
      }
      lkey = gk[0];
#pragma unroll
      for (int gi = 1; gi < 4; gi++) lkey = (gk[gi] < lkey) ? gk[gi] : lkey;
    }
  }
}

// ---------------------------------------------------------------------------
// Register-file MFMA GEMM: ONE wave per 64x32 tile, K=256. No LDS/barriers.
// MODE 0: C = acc (qkv, N=768)   MODE 1: C = gelu(acc+bias) + colsum atomics
// ---------------------------------------------------------------------------
template <int MODE>
__global__ __launch_bounds__(64, 4) void gemm_rf(
    const ushort_t* __restrict__ A, const ushort_t* __restrict__ BT,
    const float* __restrict__ bias, float* __restrict__ C,
    float* __restrict__ part, int N) {
  constexpr int K = 256;
  int lane = threadIdx.x;
  int quad = lane >> 4, r16 = lane & 15;
  int t0 = blockIdx.x;
  int m0, n0;
  if (MODE == 0) { m0 = (t0 / 24) * 64; n0 = (t0 % 24) * 32; }
  else           { m0 = (t0 >> 3) * 64; n0 = (t0 & 7) * 32; }
  int batch = m0 >> 11;
  const ushort_t* Ap = A + (size_t)(m0 + r16) * K + quad * 8;
  const ushort_t* Bp = BT + (size_t)(n0 + r16) * K + quad * 8;
  f32x4 acc[4][2] = {};
  bf16x8 af[4], bf[2], af2[4], bf2[2];
#pragma unroll
  for (int i = 0; i < 4; i++) af[i] = *(const bf16x8*)(Ap + (size_t)i * 16 * K);
#pragma unroll
  for (int j = 0; j < 2; j++) bf[j] = *(const bf16x8*)(Bp + (size_t)j * 16 * K);
#pragma unroll
  for (int kc = 0; kc < 8; kc++) {
    if (kc < 7) {
      int ko = (kc + 1) * 32;
#pragma unroll
      for (int i = 0; i < 4; i++)
        af2[i] = *(const bf16x8*)(Ap + (size_t)i * 16 * K + ko);
#pragma unroll
      for (int j = 0; j < 2; j++)
        bf2[j] = *(const bf16x8*)(Bp + (size_t)j * 16 * K + ko);
    }
#pragma unroll
    for (int i = 0; i < 4; i++) {
      acc[i][0] = __builtin_amdgcn_mfma_f32_16x16x32_bf16(af[i], bf[0], acc[i][0], 0, 0, 0);
      acc[i][1] = __builtin_amdgcn_mfma_f32_16x16x32_bf16(af[i], bf[1], acc[i][1], 0, 0, 0);
    }
#pragma unroll
    for (int i = 0; i < 4; i++) af[i] = af2[i];
    bf[0] = bf2[0]; bf[1] = bf2[1];
  }
  float cs[2] = {};
#pragma unroll
  for (int i = 0; i < 4; i++) {
#pragma unroll
    for (int j = 0; j < 2; j++) {
      int col = n0 + j * 16 + r16;
#pragma unroll
      for (int r = 0; r < 4; r++) {
        int row = m0 + i * 16 + quad * 4 + r;
        float v = acc[i][j][r];
        if (MODE == 1) { v = gelu_fast(v + bias[col]); cs[j] += v; }
        C[(size_t)row * N + col] = v;
      }
    }
  }
  if (MODE == 1) {
#pragma unroll
    for (int j = 0; j < 2; j++) {
      cs[j] += __shfl_xor(cs[j], 16, 64);
      cs[j] += __shfl_xor(cs[j], 32, 64);
    }
    if (quad == 0) {
#pragma unroll
      for (int j = 0; j < 2; j++)
        atomicAdd(&part[batch * 256 + n0 + j * 16 + r16], cs[j]);
    }
  }
}

// ---------------------------------------------------------------------------
// HEAD GEMM with inline av-MLP: single wave per 64x32 tile. The tiny MSF MLP
// (part/2048 -> gelu fc1 -> fc2 -> pairwise softmax) is computed redundantly
// per block into LDS (~130 MFLOP aggregate, Wfc* L2-resident) -- removes the
// msf launch + its gap. Then C = extra + (A@(B*av)) + bias.
// ---------------------------------------------------------------------------
__global__ __launch_bounds__(64) void gemm_head(
    const ushort_t* __restrict__ A, const ushort_t* __restrict__ BT,
    const float* __restrict__ bias, const float* __restrict__ extra,
    const float* __restrict__ part, const float* __restrict__ Wfc1,
    const float* __restrict__ bfc1, const float* __restrict__ Wfc2,
    const float* __restrict__ bfc2, float* __restrict__ C) {
  constexpr int K = 256;
  __shared__ float sS[256], sZ[128], sA[256], sAv[256];
  int lane = threadIdx.x;
  int quad = lane >> 4, r16 = lane & 15;
  int t0 = blockIdx.x;
  int m0 = (t0 >> 3) * 64, n0 = (t0 & 7) * 32;
  int batch = m0 >> 11;
  // ---- av-MLP (wave-local; lgkm waits instead of barriers) ----
#pragma unroll
  for (int q = 0; q < 4; q++)
    sS[lane + 64 * q] = part[batch * 256 + lane + 64 * q] * (1.0f / 2048.0f);
  __builtin_amdgcn_wave_barrier();
  asm volatile("s_waitcnt lgkmcnt(0)" ::: "memory");
#pragma unroll
  for (int q = 0; q < 2; q++) {
    int tt = lane + 64 * q;
    float z = bfc1[tt];
#pragma unroll 4
    for (int i = 0; i < 256; i++) z = fmaf(sS[i], Wfc1[i * 128 + tt], z);
    sZ[tt] = gelu_fast(z);
  }
  __builtin_amdgcn_wave_barrier();
  asm volatile("s_waitcnt lgkmcnt(0)" ::: "memory");
#pragma unroll
  for (int q = 0; q < 4; q++) {
    int tt = lane + 64 * q;
    float a = bfc2[tt];
#pragma unroll 4
    for (int jx = 0; jx < 128; jx++) a = fmaf(sZ[jx], Wfc2[jx * 256 + tt], a);
    sA[tt] = a;
  }
  __builtin_amdgcn_wave_barrier();
  asm volatile("s_waitcnt lgkmcnt(0)" ::: "memory");
#pragma unroll
  for (int q = 0; q < 4; q++) {
    int tt = lane + 64 * q;
    float a = sA[tt], pA = sA[tt ^ 128];
    float mm = fmaxf(a, pA);
    float e = __expf(a - mm);
    sAv[tt] = e / (e + __expf(pA - mm));
  }
  __builtin_amdgcn_wave_barrier();
  asm volatile("s_waitcnt lgkmcnt(0)" ::: "memory");
  // ---- MFMA tile with av folded into B-fragments ----
  const ushort_t* Ap = A + (size_t)(m0 + r16) * K + quad * 8;
  const ushort_t* Bp = BT + (size_t)(n0 + r16) * K + quad * 8;
  f32x4 acc[4][2] = {};
  bf16x8 af[4], bf[2], af2[4], bf2[2];
#pragma unroll
  for (int i = 0; i < 4; i++) af[i] = *(const bf16x8*)(Ap + (size_t)i * 16 * K);
#pragma unroll
  for (int j = 0; j < 2; j++) bf[j] = *(const bf16x8*)(Bp + (size_t)j * 16 * K);
#pragma unroll
  for (int kc = 0; kc < 8; kc++) {
    if (kc < 7) {
      int ko = (kc + 1) * 32;
#pragma unroll
      for (int i = 0; i < 4; i++)
        af2[i] = *(const bf16x8*)(Ap + (size_t)i * 16 * K + ko);
#pragma unroll
      for (int j = 0; j < 2; j++)
        bf2[j] = *(const bf16x8*)(Bp + (size_t)j * 16 * K + ko);
    }
    bf16x8 b0 = bf[0], b1 = bf[1];
#pragma unroll
    for (int e = 0; e < 8; e++) {
      float avv = sAv[kc * 32 + quad * 8 + e];
      b0[e] = (short)f2bf(bf2f((ushort_t)b0[e]) * avv);
      b1[e] = (short)f2bf(bf2f((ushort_t)b1[e]) * avv);
    }
#pragma unroll
    for (int i = 0; i < 4; i++) {
      acc[i][0] = __builtin_amdgcn_mfma_f32_16x16x32_bf16(af[i], b0, acc[i][0], 0, 0, 0);
      acc[i][1] = __builtin_amdgcn_mfma_f32_16x16x32_bf16(af[i], b1, acc[i][1], 0, 0, 0);
    }
#pragma unroll
    for (int i = 0; i < 4; i++) af[i] = af2[i];
    bf[0] = bf2[0]; bf[1] = bf2[1];
  }
#pragma unroll
  for (int i = 0; i < 4; i++) {
#pragma unroll
    for (int j = 0; j < 2; j++) {
      int col = n0 + j * 16 + r16;
#pragma unroll
      for (int r = 0; r < 4; r++) {
        int row = m0 + i * 16 + quad * 4 + r;
        float v = extra[(size_t)row * 256 + col] + acc[i][j][r] + bias[col];
        C[(size_t)row * 256 + col] = v;
      }
    }
  }
}

// ---------------------------------------------------------------------------
// Attention v5: grid (8192, 2), block = 128 = one (b,n,group) -- no group
// imbalance inside a block. ONE-PASS online softmax: per j, 5-step DPP reduce
// folds q.k*SCALE + attn_rel; readlane(31/63) broadcasts the two half-wave
// logits; (m, den, num) run per thread. k AND v load from the same SGPR row
// base in the same iteration (2x loads in flight), rp never stored, no logits
// LDS, no lgkm drains in the loop.
// ---------------------------------------------------------------------------
template <int NK>
__device__ __forceinline__ float attn_loop(
    const float* __restrict__ qkvb, const int* sidx, const float4* srel,
    int g, int c, int lane, float qS, float w0, float w1, float w2, float bb) {
  float m = -3.4e38f, den = 0.f, num = 0.f;
#pragma unroll
  for (int j = 0; j < NK; j++) {
    int jj = __builtin_amdgcn_readfirstlane(sidx[j]);   // wave-uniform -> SGPR
    float4 rr = srel[j];                                // LDS broadcast
    const float* kb = qkvb + (size_t)jj * QKVW + 256 + g * 128;
    float kv = kb[c];                                   // coalesced k row
    float vv = kb[256 + c];                             // coalesced v row
    float x = fmaf(rr.x, w0, fmaf(rr.y, w1, fmaf(rr.z, w2, bb)));
    float r = gelu_tanh(x);
    float u = head32_reduce(fmaf(qS, kv, r));
    float l0 = __int_as_float(__builtin_amdgcn_readlane(__float_as_int(u), 31));
    float l1 = __int_as_float(__builtin_amdgcn_readlane(__float_as_int(u), 63));
    float logit = (lane < 32) ? l0 : l1;
    float mn = fmaxf(m, logit);
    float corr = __expf(m - mn);    // first iter: exp(-huge) = 0
    float e = __expf(logit - mn);
    den = fmaf(den, corr, e);
    num = fmaf(num, corr, e * (vv + r));
    m = mn;
  }
  return num * __builtin_amdgcn_rcpf(den);
}

__global__ __launch_bounds__(128) void attn_kernel(
    const float* __restrict__ qkv, const float* __restrict__ pos,
    const int* __restrict__ knn,
    const float* __restrict__ Wp0, const float* __restrict__ bp0,
    const float* __restrict__ Wp1, const float* __restrict__ bp1,
    ushort_t* __restrict__ xcat) {
  const float SCALE = 0.17677669529663687f;  // 32^-0.5
  int u = blockIdx.x;           // (b,n)
  int g = blockIdx.y;           // group
  int b = u >> 11, n = u & (NPT - 1);
  int c = threadIdx.x;          // channel within group, 0..127
  int wave = c >> 6, lane = c & 63;
  __shared__ int s_idx[2][32];
  __shared__ float4 s_rel[2][32];
  const float* qkvb = qkv + (size_t)b * NPT * QKVW;
  if (lane < 32) {
    int j = knn[(size_t)u * 32 + lane];
    s_idx[wave][lane] = j;
    const float* pn = pos + ((size_t)b * NPT + n) * 3;
    const float* pj = pos + ((size_t)b * NPT + j) * 3;
    s_rel[wave][lane] = make_float4(pn[0] - pj[0], pn[1] - pj[1],
                                    pn[2] - pj[2], 0.f);
  }
  __builtin_amdgcn_wave_barrier();
  asm volatile("s_waitcnt lgkmcnt(0)" ::: "memory");
  const float* Wp = g ? Wp1 : Wp0;
  const float* bp = g ? bp1 : bp0;
  float w0 = Wp[c], w1 = Wp[128 + c], w2 = Wp[256 + c], bb = bp[c];
  float qS = qkvb[(size_t)n * QKVW + g * 128 + c] * SCALE;
  float o = (g == 0)
      ? attn_loop<16>(qkvb, s_idx[wave], s_rel[wave], g, c, lane, qS, w0, w1, w2, bb)
      : attn_loop<32>(qkvb, s_idx[wave], s_rel[wave], g, c, lane, qS, w0, w1, w2, bb);
  xcat[((size_t)b * NPT + n) * DIM_ + g * 128 + c] = f2bf(o);
}

// ---------------------------------------------------------------------------
extern "C" void kernel_launch(void* const* d_in, const int* in_sizes, int n_in,
                              void* d_out, int out_size, void* d_ws, size_t ws_size,
                              hipStream_t stream) {
  const float* x     = (const float*)d_in[0];
  const float* pos   = (const float*)d_in[1];
  const float* Wqkv  = (const float*)d_in[2];
  const float* Wp0   = (const float*)d_in[3];
  const float* bp0   = (const float*)d_in[4];
  const float* Wp1   = (const float*)d_in[5];
  const float* bp1   = (const float*)d_in[6];
  const float* Wproj = (const float*)d_in[7];
  const float* bproj = (const float*)d_in[8];
  const float* Wfc1  = (const float*)d_in[9];
  const float* bfc1  = (const float*)d_in[10];
  const float* Wfc2  = (const float*)d_in[11];
  const float* bfc2  = (const float*)d_in[12];
  const float* Whead = (const float*)d_in[13];
  const float* bhead = (const float*)d_in[14];
  float* out = (float*)d_out;

  char* ws = (char*)d_ws;
  size_t off = 0;
  int* idx = (int*)(ws + off);              off += (size_t)B_ * NPT * 32 * 4;   // 1.0 MB
  float* qkv = (float*)(ws + off);          off += (size_t)B_ * NPT * QKVW * 4; // 25.2 MB (also fp)
  float* fp = qkv;  // feats_proj reuses qkv region (qkv dead after attn)
  ushort_t* xbf = (ushort_t*)(ws + off);    off += (size_t)B_ * NPT * DIM_ * 2; // 4.2 MB
  ushort_t* xcat = xbf;  // xbf dead after gemm0
  ushort_t* WqkvT = (ushort_t*)(ws + off);  off += (size_t)QLEN * 2;
  ushort_t* WprojT = (ushort_t*)(ws + off); off += (size_t)PLEN * 2;
  ushort_t* WheadT = (ushort_t*)(ws + off); off += (size_t)PLEN * 2;
  float* part = (float*)(ws + off);         off += 1024 * 4;

  const int M = B_ * NPT;  // 8192

  prep_kernel<<<4096, 256, 0, stream>>>(pos, x, Wqkv, Wproj, Whead,
                                        idx, xbf, WqkvT, WprojT, WheadT, part);
  gemm_rf<0><<<3072, 64, 0, stream>>>(xbf, WqkvT, nullptr, qkv, nullptr, QKVW);
  attn_kernel<<<dim3(M, 2), 128, 0, stream>>>(qkv, pos, idx,
                                              Wp0, bp0, Wp1, bp1, xcat);
  gemm_rf<1><<<1024, 64, 0, stream>>>(xcat, WprojT, bproj, fp, part, DIM_);
  gemm_head<<<1024, 64, 0, stream>>>(xcat, WheadT, bhead, fp, part,
                                     Wfc1, bfc1, Wfc2, bfc2, out);
}

// Round 12
// 248.989 us; speedup vs baseline: 1.2096x; 1.2096x over previous
//
#include <hip/hip_runtime.h>
#include <cstdint>
#include <cstddef>

// Problem constants (reference: B=4, N=2048, DIM=256, heads=8, groups=2)
#define B_    4
#define NPT   2048
#define DIM_  256
#define QKVW  768   // 3*DIM
#define XLEN  2097152   // 8192*256
#define QLEN  196608    // 768*256
#define PLEN  65536     // 256*256
#define TOTC  (XLEN + QLEN + 2 * PLEN)  // 2424832

typedef unsigned short ushort_t;
typedef short bf16x8 __attribute__((ext_vector_type(8)));
typedef float f32x4 __attribute__((ext_vector_type(4)));

__device__ __forceinline__ float gelu_f(float x) {
  return 0.5f * x * (1.0f + erff(x * 0.70710678118654752440f));
}

// Fast gelu: A&S 7.1.26 erf (max abs err 1.5e-7).
__device__ __forceinline__ float gelu_fast(float x) {
  const float is2 = 0.70710678118654752440f;
  float z = x * is2;
  float az = __builtin_fabsf(z);
  float t = __builtin_amdgcn_rcpf(fmaf(0.3275911f, az, 1.0f));
  float p = fmaf(1.061405429f, t, -1.453152027f);
  p = fmaf(p, t, 1.421413741f);
  p = fmaf(p, t, -0.284496736f);
  p = fmaf(p, t, 0.254829592f);
  p = p * t;
  float e = __expf(-az * az);
  float er = fmaf(-p, e, 1.0f);
  er = __builtin_copysignf(er, x);
  return 0.5f * x * (1.0f + er);
}

// tanh-form gelu (~11 VALU; dev from erf-gelu ~1e-3 << 3.7e-2 threshold).
__device__ __forceinline__ float gelu_tanh(float x) {
  float x2 = x * x;
  float z2 = x * fmaf(0.0713548163f, x2, 1.5957691216f);
  float e = __expf(z2);
  float t = __builtin_amdgcn_rcpf(e + 1.0f);
  float th = fmaf(-2.0f, t, 1.0f);
  return 0.5f * x * (1.0f + th);
}

__device__ __forceinline__ ushort_t f2bf(float f) {
  unsigned u = __float_as_uint(f);
  unsigned r = (u + 0x7fffu + ((u >> 16) & 1u)) >> 16;
  return (ushort_t)r;
}
__device__ __forceinline__ float bf2f(ushort_t h) {
  return __uint_as_float(((unsigned)h) << 16);
}

template <int CTRL>
__device__ __forceinline__ void dppmin_step(int& lo, int& hi) {
  int olo = __builtin_amdgcn_update_dpp(lo, lo, CTRL, 0xf, 0xf, false);
  int ohi = __builtin_amdgcn_update_dpp(hi, hi, CTRL, 0xf, 0xf, false);
  unsigned long long o = ((unsigned long long)(unsigned)ohi << 32) | (unsigned)olo;
  unsigned long long c = ((unsigned long long)(unsigned)hi << 32) | (unsigned)lo;
  if (o < c) { lo = olo; hi = ohi; }
}
template <int CTRL>
__device__ __forceinline__ float dpp_addf(float x) {
  int s = __builtin_amdgcn_update_dpp(0, __float_as_int(x), CTRL, 0xf, 0xf, false);
  return x + __int_as_float(s);
}
// 32-lane sum within each half-wave: lane31 = sum(0..31), lane63 = sum(32..63)
__device__ __forceinline__ float head32_reduce(float u) {
  u = dpp_addf<0x111>(u);
  u = dpp_addf<0x112>(u);
  u = dpp_addf<0x114>(u);
  u = dpp_addf<0x118>(u);
  u = dpp_addf<0x142>(u);
  return u;
}

// scale a bf16x8 B-fragment by av[k] (8 consecutive k's from global, L1-hot)
__device__ __forceinline__ bf16x8 scale_bf(bf16x8 v, const float* avk) {
  bf16x8 r;
#pragma unroll
  for (int e = 0; e < 8; e++) {
    float f = bf2f((ushort_t)v[e]) * avk[e];
    r[e] = (short)f2bf(f);
  }
  return r;
}

// ---------------------------------------------------------------------------
// PREP: fused KNN + convert (disjoint block ranges). Blocks 0..2047: KNN, one
// wave per query (DPP wave-min, packed u64 keys). Blocks 2048..4095: bf16
// convert (coalesced reads) + part zero.
// ---------------------------------------------------------------------------
__global__ __launch_bounds__(256) void prep_kernel(
    const float* __restrict__ pos, const float* __restrict__ x,
    const float* __restrict__ Wqkv, const float* __restrict__ Wproj,
    const float* __restrict__ Whead, int* __restrict__ idx_out,
    ushort_t* __restrict__ xbf, ushort_t* __restrict__ WqkvT,
    ushort_t* __restrict__ WprojT, ushort_t* __restrict__ WheadT,
    float* __restrict__ part) {
  int tid = threadIdx.x;
  if (blockIdx.x >= 2048) {
    int base = (blockIdx.x - 2048) * 256 + tid;
    if (base < 1024) part[base] = 0.f;
    for (int i = base; i < TOTC; i += 2048 * 256) {
      if (i < XLEN) {
        xbf[i] = f2bf(x[i]);
      } else if (i < XLEN + QLEN) {
        int e = i - XLEN;                  // input-major: coalesced read
        int k = e / 768, n = e - k * 768;
        WqkvT[n * 256 + k] = f2bf(Wqkv[e]);
      } else if (i < XLEN + QLEN + PLEN) {
        int e = i - XLEN - QLEN;
        int k = e >> 8, n = e & 255;
        WprojT[n * 256 + k] = f2bf(Wproj[e]);
      } else {
        int e = i - XLEN - QLEN - PLEN;
        int k = e >> 8, n = e & 255;
        WheadT[n * 256 + k] = f2bf(Whead[e]);
      }
    }
    return;
  }
  int wave = tid >> 6, lane = tid & 63;
  int wq = blockIdx.x * 4 + wave;
  int b = wq >> 11, n = wq & (NPT - 1);
  const float* pb = pos + (size_t)b * NPT * 3;
  float qx = pb[n * 3 + 0], qy = pb[n * 3 + 1], qz = pb[n * 3 + 2];
  unsigned long long keys[32];
  {
#pragma clang fp contract(off)
#pragma unroll
    for (int s = 0; s < 32; s++) {
      int j = lane + (s << 6);
      float dx = qx - pb[j * 3 + 0];
      float dy = qy - pb[j * 3 + 1];
      float dz = qz - pb[j * 3 + 2];
      float d = dx * dx;
      d = d + dy * dy;
      d = d + dz * dz;
      keys[s] = ((unsigned long long)__float_as_uint(d) << 32) | (unsigned int)j;
    }
  }
  unsigned long long gk[4];
#pragma unroll
  for (int gi = 0; gi < 4; gi++) {
    unsigned long long m = keys[gi * 8];
#pragma unroll
    for (int s = 1; s < 8; s++) {
      unsigned long long c = keys[gi * 8 + s];
      m = (c < m) ? c : m;
    }
    gk[gi] = m;
  }
  unsigned long long lkey = gk[0];
#pragma unroll
  for (int gi = 1; gi < 4; gi++) lkey = (gk[gi] < lkey) ? gk[gi] : lkey;
  int* outp = idx_out + (size_t)wq * 32;
  for (int r = 0; r < 32; r++) {
    int lo = (int)(unsigned)(lkey & 0xffffffffULL);
    int hi = (int)(unsigned)(lkey >> 32);
    dppmin_step<0x111>(lo, hi);
    dppmin_step<0x112>(lo, hi);
    dppmin_step<0x114>(lo, hi);
    dppmin_step<0x118>(lo, hi);
    dppmin_step<0x142>(lo, hi);
    dppmin_step<0x143>(lo, hi);
    unsigned int glo = (unsigned int)__builtin_amdgcn_readlane(lo, 63);
    unsigned int ghi = (unsigned int)__builtin_amdgcn_readlane(hi, 63);
    unsigned long long g = ((unsigned long long)ghi << 32) | glo;
    if (lkey == g) {
      outp[r] = (int)glo;
#pragma unroll
      for (int gi = 0; gi < 4; gi++) {
        if (gk[gi] == g) {
          unsigned long long m = ~0ULL;
#pragma unroll
          for (int s = 0; s < 8; s++) {
            unsigned long long c = keys[gi * 8 + s];
            if (c == g) { c = ~0ULL; keys[gi * 8 + s] = c; }
            m = (c < m) ? c : m;
          }
          gk[gi] = m;
        }
      }
      lkey = gk[0];
#pragma unroll
      for (int gi = 1; gi < 4; gi++) lkey = (gk[gi] < lkey) ? gk[gi] : lkey;
    }
  }
}

// ---------------------------------------------------------------------------
// Register-file MFMA GEMM: ONE wave per 64x32 tile, K=256. No LDS/barriers.
// MODE 0: C = acc (qkv, N=768)
// MODE 1: C = gelu(acc+bias) + colsum atomics (feats_proj)
// MODE 2: C = extra + (A@(B*av)) + bias (av from global, L1-hot — R11's
//         in-kernel av-MLP was a 90-116 µs latency disaster at 1 wave/SIMD)
// ---------------------------------------------------------------------------
template <int MODE>
__global__ __launch_bounds__(64, 4) void gemm_rf(
    const ushort_t* __restrict__ A, const ushort_t* __restrict__ BT,
    const float* __restrict__ bias, const float* __restrict__ extra,
    float* __restrict__ C, float* __restrict__ part,
    const float* __restrict__ av, int N) {
  constexpr int K = 256;
  int lane = threadIdx.x;
  int quad = lane >> 4, r16 = lane & 15;
  int t0 = blockIdx.x;
  int m0, n0;
  if (MODE == 0) { m0 = (t0 / 24) * 64; n0 = (t0 % 24) * 32; }
  else           { m0 = (t0 >> 3) * 64; n0 = (t0 & 7) * 32; }
  int batch = m0 >> 11;
  const ushort_t* Ap = A + (size_t)(m0 + r16) * K + quad * 8;
  const ushort_t* Bp = BT + (size_t)(n0 + r16) * K + quad * 8;
  f32x4 acc[4][2] = {};
  bf16x8 af[4], bf[2], af2[4], bf2[2];
#pragma unroll
  for (int i = 0; i < 4; i++) af[i] = *(const bf16x8*)(Ap + (size_t)i * 16 * K);
#pragma unroll
  for (int j = 0; j < 2; j++) bf[j] = *(const bf16x8*)(Bp + (size_t)j * 16 * K);
#pragma unroll
  for (int kc = 0; kc < 8; kc++) {
    if (kc < 7) {
      int ko = (kc + 1) * 32;
#pragma unroll
      for (int i = 0; i < 4; i++)
        af2[i] = *(const bf16x8*)(Ap + (size_t)i * 16 * K + ko);
#pragma unroll
      for (int j = 0; j < 2; j++)
        bf2[j] = *(const bf16x8*)(Bp + (size_t)j * 16 * K + ko);
    }
    bf16x8 b0 = bf[0], b1 = bf[1];
    if (MODE == 2) {
      const float* avk = av + batch * 256 + kc * 32 + quad * 8;
      b0 = scale_bf(b0, avk);
      b1 = scale_bf(b1, avk);
    }
#pragma unroll
    for (int i = 0; i < 4; i++) {
      acc[i][0] = __builtin_amdgcn_mfma_f32_16x16x32_bf16(af[i], b0, acc[i][0], 0, 0, 0);
      acc[i][1] = __builtin_amdgcn_mfma_f32_16x16x32_bf16(af[i], b1, acc[i][1], 0, 0, 0);
    }
#pragma unroll
    for (int i = 0; i < 4; i++) af[i] = af2[i];
    bf[0] = bf2[0]; bf[1] = bf2[1];
  }
  float cs[2] = {};
#pragma unroll
  for (int i = 0; i < 4; i++) {
#pragma unroll
    for (int j = 0; j < 2; j++) {
      int col = n0 + j * 16 + r16;
#pragma unroll
      for (int r = 0; r < 4; r++) {
        int row = m0 + i * 16 + quad * 4 + r;
        float v = acc[i][j][r];
        if (MODE == 1) { v = gelu_fast(v + bias[col]); cs[j] += v; }
        else if (MODE == 2) v = extra[(size_t)row * 256 + col] + v + bias[col];
        C[(size_t)row * N + col] = v;
      }
    }
  }
  if (MODE == 1) {
#pragma unroll
    for (int j = 0; j < 2; j++) {
      cs[j] += __shfl_xor(cs[j], 16, 64);
      cs[j] += __shfl_xor(cs[j], 32, 64);
    }
    if (quad == 0) {
#pragma unroll
      for (int j = 0; j < 2; j++)
        atomicAdd(&part[batch * 256 + n0 + j * 16 + r16], cs[j]);
    }
  }
}

// ---------------------------------------------------------------------------
// Attention v5 (R11, kept — pushed attn out of top-5): grid (8192,2), block =
// 128 = one (b,n,group). One-pass online softmax; per j: 5-step DPP reduce
// folds q.k*SCALE + attn_rel, readlane(31/63) broadcasts the two half-wave
// logits, (m,den,num) run per thread; k and v load from the same SGPR row
// base in the same iteration; rp never stored; no logits LDS.
// ---------------------------------------------------------------------------
template <int NK>
__device__ __forceinline__ float attn_loop(
    const float* __restrict__ qkvb, const int* sidx, const float4* srel,
    int g, int c, int lane, float qS, float w0, float w1, float w2, float bb) {
  float m = -3.4e38f, den = 0.f, num = 0.f;
#pragma unroll
  for (int j = 0; j < NK; j++) {
    int jj = __builtin_amdgcn_readfirstlane(sidx[j]);   // wave-uniform -> SGPR
    float4 rr = srel[j];                                // LDS broadcast
    const float* kb = qkvb + (size_t)jj * QKVW + 256 + g * 128;
    float kv = kb[c];                                   // coalesced k row
    float vv = kb[256 + c];                             // coalesced v row
    float x = fmaf(rr.x, w0, fmaf(rr.y, w1, fmaf(rr.z, w2, bb)));
    float r = gelu_tanh(x);
    float u = head32_reduce(fmaf(qS, kv, r));
    float l0 = __int_as_float(__builtin_amdgcn_readlane(__float_as_int(u), 31));
    float l1 = __int_as_float(__builtin_amdgcn_readlane(__float_as_int(u), 63));
    float logit = (lane < 32) ? l0 : l1;
    float mn = fmaxf(m, logit);
    float corr = __expf(m - mn);    // first iter: exp(-huge) = 0
    float e = __expf(logit - mn);
    den = fmaf(den, corr, e);
    num = fmaf(num, corr, e * (vv + r));
    m = mn;
  }
  return num * __builtin_amdgcn_rcpf(den);
}

__global__ __launch_bounds__(128) void attn_kernel(
    const float* __restrict__ qkv, const float* __restrict__ pos,
    const int* __restrict__ knn,
    const float* __restrict__ Wp0, const float* __restrict__ bp0,
    const float* __restrict__ Wp1, const float* __restrict__ bp1,
    ushort_t* __restrict__ xcat) {
  const float SCALE = 0.17677669529663687f;  // 32^-0.5
  int u = blockIdx.x;           // (b,n)
  int g = blockIdx.y;           // group
  int b = u >> 11, n = u & (NPT - 1);
  int c = threadIdx.x;          // channel within group, 0..127
  int wave = c >> 6, lane = c & 63;
  __shared__ int s_idx[2][32];
  __shared__ float4 s_rel[2][32];
  const float* qkvb = qkv + (size_t)b * NPT * QKVW;
  if (lane < 32) {
    int j = knn[(size_t)u * 32 + lane];
    s_idx[wave][lane] = j;
    const float* pn = pos + ((size_t)b * NPT + n) * 3;
    const float* pj = pos + ((size_t)b * NPT + j) * 3;
    s_rel[wave][lane] = make_float4(pn[0] - pj[0], pn[1] - pj[1],
                                    pn[2] - pj[2], 0.f);
  }
  __builtin_amdgcn_wave_barrier();
  asm volatile("s_waitcnt lgkmcnt(0)" ::: "memory");
  const float* Wp = g ? Wp1 : Wp0;
  const float* bp = g ? bp1 : bp0;
  float w0 = Wp[c], w1 = Wp[128 + c], w2 = Wp[256 + c], bb = bp[c];
  float qS = qkvb[(size_t)n * QKVW + g * 128 + c] * SCALE;
  float o = (g == 0)
      ? attn_loop<16>(qkvb, s_idx[wave], s_rel[wave], g, c, lane, qS, w0, w1, w2, bb)
      : attn_loop<32>(qkvb, s_idx[wave], s_rel[wave], g, c, lane, qS, w0, w1, w2, bb);
  xcat[((size_t)b * NPT + n) * DIM_ + g * 128 + c] = f2bf(o);
}

// ---------------------------------------------------------------------------
// MSF av only (R10 form — tiny, never in top-5): S = part/2048 ->
// Z = gelu(S@Wfc1+b) -> a = Z@Wfc2+b -> av = pairwise softmax.
// ---------------------------------------------------------------------------
__global__ __launch_bounds__(256) void msf_av_kernel(
    const float* __restrict__ part, const float* __restrict__ Wfc1,
    const float* __restrict__ bfc1, const float* __restrict__ Wfc2,
    const float* __restrict__ bfc2, float* __restrict__ av_out) {
  int b = blockIdx.x, t = threadIdx.x;
  __shared__ float S[256], Z[128], A[256];
  S[t] = part[b * 256 + t] * (1.0f / 2048.0f);
  __syncthreads();
  if (t < 128) {
    float z = bfc1[t];
    for (int i = 0; i < 256; i++) z += S[i] * Wfc1[i * 128 + t];
    Z[t] = gelu_f(z);
  }
  __syncthreads();
  float a = bfc2[t];
  for (int j = 0; j < 128; j++) a += Z[j] * Wfc2[j * 256 + t];
  A[t] = a;
  __syncthreads();
  float pA = A[t ^ 128];
  float m = fmaxf(a, pA);
  float e = expf(a - m);
  av_out[b * 256 + t] = e / (e + expf(pA - m));
}

// ---------------------------------------------------------------------------
extern "C" void kernel_launch(void* const* d_in, const int* in_sizes, int n_in,
                              void* d_out, int out_size, void* d_ws, size_t ws_size,
                              hipStream_t stream) {
  const float* x     = (const float*)d_in[0];
  const float* pos   = (const float*)d_in[1];
  const float* Wqkv  = (const float*)d_in[2];
  const float* Wp0   = (const float*)d_in[3];
  const float* bp0   = (const float*)d_in[4];
  const float* Wp1   = (const float*)d_in[5];
  const float* bp1   = (const float*)d_in[6];
  const float* Wproj = (const float*)d_in[7];
  const float* bproj = (const float*)d_in[8];
  const float* Wfc1  = (const float*)d_in[9];
  const float* bfc1  = (const float*)d_in[10];
  const float* Wfc2  = (const float*)d_in[11];
  const float* bfc2  = (const float*)d_in[12];
  const float* Whead = (const float*)d_in[13];
  const float* bhead = (const float*)d_in[14];
  float* out = (float*)d_out;

  char* ws = (char*)d_ws;
  size_t off = 0;
  int* idx = (int*)(ws + off);              off += (size_t)B_ * NPT * 32 * 4;   // 1.0 MB
  float* qkv = (float*)(ws + off);          off += (size_t)B_ * NPT * QKVW * 4; // 25.2 MB (also fp)
  float* fp = qkv;  // feats_proj reuses qkv region (qkv dead after attn)
  ushort_t* xbf = (ushort_t*)(ws + off);    off += (size_t)B_ * NPT * DIM_ * 2; // 4.2 MB
  ushort_t* xcat = xbf;  // xbf dead after gemm0
  ushort_t* WqkvT = (ushort_t*)(ws + off);  off += (size_t)QLEN * 2;
  ushort_t* WprojT = (ushort_t*)(ws + off); off += (size_t)PLEN * 2;
  ushort_t* WheadT = (ushort_t*)(ws + off); off += (size_t)PLEN * 2;
  float* part = (float*)(ws + off);         off += 1024 * 4;
  float* av = (float*)(ws + off);           off += 1024 * 4;

  const int M = B_ * NPT;  // 8192

  prep_kernel<<<4096, 256, 0, stream>>>(pos, x, Wqkv, Wproj, Whead,
                                        idx, xbf, WqkvT, WprojT, WheadT, part);
  gemm_rf<0><<<3072, 64, 0, stream>>>(xbf, WqkvT, nullptr, nullptr,
                                      qkv, nullptr, nullptr, QKVW);
  attn_kernel<<<dim3(M, 2), 128, 0, stream>>>(qkv, pos, idx,
                                              Wp0, bp0, Wp1, bp1, xcat);
  gemm_rf<1><<<1024, 64, 0, stream>>>(xcat, WprojT, bproj, nullptr,
                                      fp, part, nullptr, DIM_);
  msf_av_kernel<<<B_, 256, 0, stream>>>(part, Wfc1, bfc1, Wfc2, bfc2, av);
  gemm_rf<2><<<1024, 64, 0, stream>>>(xcat, WheadT, bhead, fp,
                                      out, nullptr, av, DIM_);
}

// Round 13
// 233.106 us; speedup vs baseline: 1.2920x; 1.0681x over previous
//
#include <hip/hip_runtime.h>
#include <cstdint>
#include <cstddef>

// Problem constants (reference: B=4, N=2048, DIM=256, heads=8, groups=2)
#define B_    4
#define NPT   2048
#define DIM_  256
#define QKVW  768   // 3*DIM
#define XLEN  2097152   // 8192*256
#define QLEN  196608    // 768*256
#define PLEN  65536     // 256*256
#define TOTC  (XLEN + QLEN + 2 * PLEN)  // 2424832

typedef unsigned short ushort_t;
typedef unsigned long long u64;
typedef short bf16x8 __attribute__((ext_vector_type(8)));
typedef float f32x4 __attribute__((ext_vector_type(4)));

__device__ __forceinline__ float gelu_f(float x) {
  return 0.5f * x * (1.0f + erff(x * 0.70710678118654752440f));
}

// Fast gelu: A&S 7.1.26 erf (max abs err 1.5e-7).
__device__ __forceinline__ float gelu_fast(float x) {
  const float is2 = 0.70710678118654752440f;
  float z = x * is2;
  float az = __builtin_fabsf(z);
  float t = __builtin_amdgcn_rcpf(fmaf(0.3275911f, az, 1.0f));
  float p = fmaf(1.061405429f, t, -1.453152027f);
  p = fmaf(p, t, 1.421413741f);
  p = fmaf(p, t, -0.284496736f);
  p = fmaf(p, t, 0.254829592f);
  p = p * t;
  float e = __expf(-az * az);
  float er = fmaf(-p, e, 1.0f);
  er = __builtin_copysignf(er, x);
  return 0.5f * x * (1.0f + er);
}

// tanh-form gelu (~11 VALU; dev from erf-gelu ~1e-3 << 3.7e-2 threshold).
__device__ __forceinline__ float gelu_tanh(float x) {
  float x2 = x * x;
  float z2 = x * fmaf(0.0713548163f, x2, 1.5957691216f);
  float e = __expf(z2);
  float t = __builtin_amdgcn_rcpf(e + 1.0f);
  float th = fmaf(-2.0f, t, 1.0f);
  return 0.5f * x * (1.0f + th);
}

__device__ __forceinline__ ushort_t f2bf(float f) {
  unsigned u = __float_as_uint(f);
  unsigned r = (u + 0x7fffu + ((u >> 16) & 1u)) >> 16;
  return (ushort_t)r;
}
__device__ __forceinline__ float bf2f(ushort_t h) {
  return __uint_as_float(((unsigned)h) << 16);
}

template <int CTRL>
__device__ __forceinline__ void dppmin_step(int& lo, int& hi) {
  int olo = __builtin_amdgcn_update_dpp(lo, lo, CTRL, 0xf, 0xf, false);
  int ohi = __builtin_amdgcn_update_dpp(hi, hi, CTRL, 0xf, 0xf, false);
  u64 o = ((u64)(unsigned)ohi << 32) | (unsigned)olo;
  u64 c = ((u64)(unsigned)hi << 32) | (unsigned)lo;
  if (o < c) { lo = olo; hi = ohi; }
}
template <int CTRL>
__device__ __forceinline__ float dpp_addf(float x) {
  int s = __builtin_amdgcn_update_dpp(0, __float_as_int(x), CTRL, 0xf, 0xf, false);
  return x + __int_as_float(s);
}
template <int CTRL>
__device__ __forceinline__ int dpp_addi(int x) {
  int s = __builtin_amdgcn_update_dpp(0, x, CTRL, 0xf, 0xf, false);
  return x + s;
}
// 32-lane sum within each half-wave: lane31 = sum(0..31), lane63 = sum(32..63)
__device__ __forceinline__ float head32_reduce(float u) {
  u = dpp_addf<0x111>(u);
  u = dpp_addf<0x112>(u);
  u = dpp_addf<0x114>(u);
  u = dpp_addf<0x118>(u);
  u = dpp_addf<0x142>(u);
  return u;
}
// full 64-lane int sum -> lane 63
__device__ __forceinline__ int wave_sum_i(int x) {
  x = dpp_addi<0x111>(x);
  x = dpp_addi<0x112>(x);
  x = dpp_addi<0x114>(x);
  x = dpp_addi<0x118>(x);
  x = dpp_addi<0x142>(x);
  x = dpp_addi<0x143>(x);
  return x;
}
// full 64-lane u64 min -> lane 63
__device__ __forceinline__ u64 wave_min64(u64 k) {
  int lo = (int)(unsigned)(k & 0xffffffffULL);
  int hi = (int)(unsigned)(k >> 32);
  dppmin_step<0x111>(lo, hi);
  dppmin_step<0x112>(lo, hi);
  dppmin_step<0x114>(lo, hi);
  dppmin_step<0x118>(lo, hi);
  dppmin_step<0x142>(lo, hi);
  dppmin_step<0x143>(lo, hi);
  unsigned glo = (unsigned)__builtin_amdgcn_readlane(lo, 63);
  unsigned ghi = (unsigned)__builtin_amdgcn_readlane(hi, 63);
  return ((u64)ghi << 32) | glo;
}

// scale a bf16x8 B-fragment by av[k] (8 consecutive k's from global, L1-hot)
__device__ __forceinline__ bf16x8 scale_bf(bf16x8 v, const float* avk) {
  bf16x8 r;
#pragma unroll
  for (int e = 0; e < 8; e++) {
    float f = bf2f((ushort_t)v[e]) * avk[e];
    r[e] = (short)f2bf(f);
  }
  return r;
}

// ---------------------------------------------------------------------------
// PREP: fused KNN + convert (disjoint block ranges).
// KNN v4 (R13): bisect -> compact -> extract.
//   R12's extract-from-2048 paid ~130 instr/round for the owner-lane removal
//   rescan (exec-masked but wave-issued) = ~6K instr/query. Now: (1) bisect a
//   uint threshold on dist bits until 32 <= count <= 64 (counts ~halve/iter,
//   ~7-10 iters x ~75 instr); (2) compact matching keys into wave-private LDS
//   (ds_add_rtn offsets; 2 slots/lane = up to 128 for tie pathologies);
//   (3) extract 32 mins from 2 keys/lane -- removal is 2 compares, winner
//   index kept in lane r's register -> one coalesced store. Exact: final
//   picks are by full 64-bit key over a pool containing the true top-32;
//   output order irrelevant (softmax is permutation-invariant; group0 reads
//   entries 0..15 = the 16 smallest, which extraction order guarantees).
// ---------------------------------------------------------------------------
__global__ __launch_bounds__(256) void prep_kernel(
    const float* __restrict__ pos, const float* __restrict__ x,
    const float* __restrict__ Wqkv, const float* __restrict__ Wproj,
    const float* __restrict__ Whead, int* __restrict__ idx_out,
    ushort_t* __restrict__ xbf, ushort_t* __restrict__ WqkvT,
    ushort_t* __restrict__ WprojT, ushort_t* __restrict__ WheadT,
    float* __restrict__ part) {
  int tid = threadIdx.x;
  if (blockIdx.x >= 2048) {
    // ---- convert path ----
    int base = (blockIdx.x - 2048) * 256 + tid;
    if (base < 1024) part[base] = 0.f;
    for (int i = base; i < TOTC; i += 2048 * 256) {
      if (i < XLEN) {
        xbf[i] = f2bf(x[i]);
      } else if (i < XLEN + QLEN) {
        int e = i - XLEN;                  // input-major: coalesced read
        int k = e / 768, n = e - k * 768;
        WqkvT[n * 256 + k] = f2bf(Wqkv[e]);
      } else if (i < XLEN + QLEN + PLEN) {
        int e = i - XLEN - QLEN;
        int k = e >> 8, n = e & 255;
        WprojT[n * 256 + k] = f2bf(Wproj[e]);
      } else {
        int e = i - XLEN - QLEN - PLEN;
        int k = e >> 8, n = e & 255;
        WheadT[n * 256 + k] = f2bf(Whead[e]);
      }
    }
    return;
  }
  // ---- KNN path (wave-private; no __syncthreads anywhere) ----
  __shared__ u64 buf[4][128];
  __shared__ unsigned cnt[4];
  int wave = tid >> 6, lane = tid & 63;
  int wq = blockIdx.x * 4 + wave;
  int b = wq >> 11, n = wq & (NPT - 1);
  const float* pb = pos + (size_t)b * NPT * 3;
  float qx = pb[n * 3 + 0], qy = pb[n * 3 + 1], qz = pb[n * 3 + 2];
  u64 keys[32];
  {
#pragma clang fp contract(off)
#pragma unroll
    for (int s = 0; s < 32; s++) {
      int j = lane + (s << 6);
      float dx = qx - pb[j * 3 + 0];
      float dy = qy - pb[j * 3 + 1];
      float dz = qz - pb[j * 3 + 2];
      float d = dx * dx;
      d = d + dy * dy;
      d = d + dz * dz;
      keys[s] = ((u64)__float_as_uint(d) << 32) | (unsigned)j;
    }
  }
  // --- bisect threshold T on dist bits: count(T) in [32, 64] (typ.) ---
  unsigned lo = 0, hi = 0x40400001u;  // sq-dists < 3.0 for pos in [0,1)^3
  for (int it = 0; it < 31 && hi - lo > 1; ++it) {
    unsigned mid = (lo + hi) >> 1;
    int c = 0;
#pragma unroll
    for (int s = 0; s < 32; s++)
      c += ((unsigned)(keys[s] >> 32) < mid) ? 1 : 0;
    c = __builtin_amdgcn_readlane(wave_sum_i(c), 63);
    if (c >= 32) { hi = mid; if (c <= 64) break; }
    else lo = mid;
  }
  unsigned T = hi;  // invariant: count(T) >= 32
  // --- compact matching keys into wave-private LDS ---
  buf[wave][lane] = ~0ULL;
  buf[wave][lane + 64] = ~0ULL;
  if (lane == 0) cnt[wave] = 0;
  __builtin_amdgcn_wave_barrier();
  asm volatile("s_waitcnt lgkmcnt(0)" ::: "memory");
  int cl = 0;
#pragma unroll
  for (int s = 0; s < 32; s++)
    cl += ((unsigned)(keys[s] >> 32) < T) ? 1 : 0;
  unsigned base = atomicAdd(&cnt[wave], (unsigned)cl);
  unsigned w = base;
#pragma unroll
  for (int s = 0; s < 32; s++) {
    if ((unsigned)(keys[s] >> 32) < T && w < 128) {
      buf[wave][w] = keys[s];
      w++;
    }
  }
  __builtin_amdgcn_wave_barrier();
  asm volatile("s_waitcnt lgkmcnt(0)" ::: "memory");
  u64 k0 = buf[wave][lane];
  u64 k1 = buf[wave][lane + 64];
  __builtin_amdgcn_wave_barrier();
  asm volatile("s_waitcnt lgkmcnt(0)" ::: "memory");
  // --- extract 32 mins; lane r keeps round r's winner ---
  int keep = 0;
  u64 lkey = (k0 < k1) ? k0 : k1;
  for (int r = 0; r < 32; r++) {
    u64 g = wave_min64(lkey);
    if (lane == r) keep = (int)(unsigned)(g & 0xffffffffULL);
    if (k0 == g) k0 = ~0ULL;
    if (k1 == g) k1 = ~0ULL;
    lkey = (k0 < k1) ? k0 : k1;
  }
  if (lane < 32) idx_out[(size_t)wq * 32 + lane] = keep;
}

// ---------------------------------------------------------------------------
// Register-file MFMA GEMM: ONE wave per 64x32 tile, K=256. No LDS/barriers.
// MODE 0: C = acc (qkv, N=768)
// MODE 1: C = gelu(acc+bias) + colsum atomics (feats_proj)
// MODE 2: C = extra + (A@(B*av)) + bias (av from global, L1-hot)
// ---------------------------------------------------------------------------
template <int MODE>
__global__ __launch_bounds__(64, 4) void gemm_rf(
    const ushort_t* __restrict__ A, const ushort_t* __restrict__ BT,
    const float* __restrict__ bias, const float* __restrict__ extra,
    float* __restrict__ C, float* __restrict__ part,
    const float* __restrict__ av, int N) {
  constexpr int K = 256;
  int lane = threadIdx.x;
  int quad = lane >> 4, r16 = lane & 15;
  int t0 = blockIdx.x;
  int m0, n0;
  if (MODE == 0) { m0 = (t0 / 24) * 64; n0 = (t0 % 24) * 32; }
  else           { m0 = (t0 >> 3) * 64; n0 = (t0 & 7) * 32; }
  int batch = m0 >> 11;
  const ushort_t* Ap = A + (size_t)(m0 + r16) * K + quad * 8;
  const ushort_t* Bp = BT + (size_t)(n0 + r16) * K + quad * 8;
  f32x4 acc[4][2] = {};
  bf16x8 af[4], bf[2], af2[4], bf2[2];
#pragma unroll
  for (int i = 0; i < 4; i++) af[i] = *(const bf16x8*)(Ap + (size_t)i * 16 * K);
#pragma unroll
  for (int j = 0; j < 2; j++) bf[j] = *(const bf16x8*)(Bp + (size_t)j * 16 * K);
#pragma unroll
  for (int kc = 0; kc < 8; kc++) {
    if (kc < 7) {
      int ko = (kc + 1) * 32;
#pragma unroll
      for (int i = 0; i < 4; i++)
        af2[i] = *(const bf16x8*)(Ap + (size_t)i * 16 * K + ko);
#pragma unroll
      for (int j = 0; j < 2; j++)
        bf2[j] = *(const bf16x8*)(Bp + (size_t)j * 16 * K + ko);
    }
    bf16x8 b0 = bf[0], b1 = bf[1];
    if (MODE == 2) {
      const float* avk = av + batch * 256 + kc * 32 + quad * 8;
      b0 = scale_bf(b0, avk);
      b1 = scale_bf(b1, avk);
    }
#pragma unroll
    for (int i = 0; i < 4; i++) {
      acc[i][0] = __builtin_amdgcn_mfma_f32_16x16x32_bf16(af[i], b0, acc[i][0], 0, 0, 0);
      acc[i][1] = __builtin_amdgcn_mfma_f32_16x16x32_bf16(af[i], b1, acc[i][1], 0, 0, 0);
    }
#pragma unroll
    for (int i = 0; i < 4; i++) af[i] = af2[i];
    bf[0] = bf2[0]; bf[1] = bf2[1];
  }
  float cs[2] = {};
#pragma unroll
  for (int i = 0; i < 4; i++) {
#pragma unroll
    for (int j = 0; j < 2; j++) {
      int col = n0 + j * 16 + r16;
#pragma unroll
      for (int r = 0; r < 4; r++) {
        int row = m0 + i * 16 + quad * 4 + r;
        float v = acc[i][j][r];
        if (MODE == 1) { v = gelu_fast(v + bias[col]); cs[j] += v; }
        else if (MODE == 2) v = extra[(size_t)row * 256 + col] + v + bias[col];
        C[(size_t)row * N + col] = v;
      }
    }
  }
  if (MODE == 1) {
#pragma unroll
    for (int j = 0; j < 2; j++) {
      cs[j] += __shfl_xor(cs[j], 16, 64);
      cs[j] += __shfl_xor(cs[j], 32, 64);
    }
    if (quad == 0) {
#pragma unroll
      for (int j = 0; j < 2; j++)
        atomicAdd(&part[batch * 256 + n0 + j * 16 + r16], cs[j]);
    }
  }
}

// ---------------------------------------------------------------------------
// Attention v5 (R11/R12): grid (8192,2), block = 128 = one (b,n,group).
// One-pass online softmax; per j: 5-step DPP reduce folds q.k*SCALE +
// attn_rel, readlane(31/63) broadcasts the two half-wave logits; k and v load
// from the same SGPR row base; rp never stored; no logits LDS.
// ---------------------------------------------------------------------------
template <int NK>
__device__ __forceinline__ float attn_loop(
    const float* __restrict__ qkvb, const int* sidx, const float4* srel,
    int g, int c, int lane, float qS, float w0, float w1, float w2, float bb) {
  float m = -3.4e38f, den = 0.f, num = 0.f;
#pragma unroll
  for (int j = 0; j < NK; j++) {
    int jj = __builtin_amdgcn_readfirstlane(sidx[j]);   // wave-uniform -> SGPR
    float4 rr = srel[j];                                // LDS broadcast
    const float* kb = qkvb + (size_t)jj * QKVW + 256 + g * 128;
    float kv = kb[c];                                   // coalesced k row
    float vv = kb[256 + c];                             // coalesced v row
    float x = fmaf(rr.x, w0, fmaf(rr.y, w1, fmaf(rr.z, w2, bb)));
    float r = gelu_tanh(x);
    float u = head32_reduce(fmaf(qS, kv, r));
    float l0 = __int_as_float(__builtin_amdgcn_readlane(__float_as_int(u), 31));
    float l1 = __int_as_float(__builtin_amdgcn_readlane(__float_as_int(u), 63));
    float logit = (lane < 32) ? l0 : l1;
    float mn = fmaxf(m, logit);
    float corr = __expf(m - mn);    // first iter: exp(-huge) = 0
    float e = __expf(logit - mn);
    den = fmaf(den, corr, e);
    num = fmaf(num, corr, e * (vv + r));
    m = mn;
  }
  return num * __builtin_amdgcn_rcpf(den);
}

__global__ __launch_bounds__(128) void attn_kernel(
    const float* __restrict__ qkv, const float* __restrict__ pos,
    const int* __restrict__ knn,
    const float* __restrict__ Wp0, const float* __restrict__ bp0,
    const float* __restrict__ Wp1, const float* __restrict__ bp1,
    ushort_t* __restrict__ xcat) {
  const float SCALE = 0.17677669529663687f;  // 32^-0.5
  int u = blockIdx.x;           // (b,n)
  int g = blockIdx.y;           // group
  int b = u >> 11, n = u & (NPT - 1);
  int c = threadIdx.x;          // channel within group, 0..127
  int wave = c >> 6, lane = c & 63;
  __shared__ int s_idx[2][32];
  __shared__ float4 s_rel[2][32];
  const float* qkvb = qkv + (size_t)b * NPT * QKVW;
  if (lane < 32) {
    int j = knn[(size_t)u * 32 + lane];
    s_idx[wave][lane] = j;
    const float* pn = pos + ((size_t)b * NPT + n) * 3;
    const float* pj = pos + ((size_t)b * NPT + j) * 3;
    s_rel[wave][lane] = make_float4(pn[0] - pj[0], pn[1] - pj[1],
                                    pn[2] - pj[2], 0.f);
  }
  __builtin_amdgcn_wave_barrier();
  asm volatile("s_waitcnt lgkmcnt(0)" ::: "memory");
  const float* Wp = g ? Wp1 : Wp0;
  const float* bp = g ? bp1 : bp0;
  float w0 = Wp[c], w1 = Wp[128 + c], w2 = Wp[256 + c], bb = bp[c];
  float qS = qkvb[(size_t)n * QKVW + g * 128 + c] * SCALE;
  float o = (g == 0)
      ? attn_loop<16>(qkvb, s_idx[wave], s_rel[wave], g, c, lane, qS, w0, w1, w2, bb)
      : attn_loop<32>(qkvb, s_idx[wave], s_rel[wave], g, c, lane, qS, w0, w1, w2, bb);
  xcat[((size_t)b * NPT + n) * DIM_ + g * 128 + c] = f2bf(o);
}

// ---------------------------------------------------------------------------
// MSF av only: S = part/2048 -> Z = gelu(S@Wfc1+b) -> a = Z@Wfc2+b ->
// av = pairwise softmax. One block per batch.
// ---------------------------------------------------------------------------
__global__ __launch_bounds__(256) void msf_av_kernel(
    const float* __restrict__ part, const float* __restrict__ Wfc1,
    const float* __restrict__ bfc1, const float* __restrict__ Wfc2,
    const float* __restrict__ bfc2, float* __restrict__ av_out) {
  int b = blockIdx.x, t = threadIdx.x;
  __shared__ float S[256], Z[128], A[256];
  S[t] = part[b * 256 + t] * (1.0f / 2048.0f);
  __syncthreads();
  if (t < 128) {
    float z = bfc1[t];
    for (int i = 0; i < 256; i++) z += S[i] * Wfc1[i * 128 + t];
    Z[t] = gelu_f(z);
  }
  __syncthreads();
  float a = bfc2[t];
  for (int j = 0; j < 128; j++) a += Z[j] * Wfc2[j * 256 + t];
  A[t] = a;
  __syncthreads();
  float pA = A[t ^ 128];
  float m = fmaxf(a, pA);
  float e = expf(a - m);
  av_out[b * 256 + t] = e / (e + expf(pA - m));
}

// ---------------------------------------------------------------------------
extern "C" void kernel_launch(void* const* d_in, const int* in_sizes, int n_in,
                              void* d_out, int out_size, void* d_ws, size_t ws_size,
                              hipStream_t stream) {
  const float* x     = (const float*)d_in[0];
  const float* pos   = (const float*)d_in[1];
  const float* Wqkv  = (const float*)d_in[2];
  const float* Wp0   = (const float*)d_in[3];
  const float* bp0   = (const float*)d_in[4];
  const float* Wp1   = (const float*)d_in[5];
  const float* bp1   = (const float*)d_in[6];
  const float* Wproj = (const float*)d_in[7];
  const float* bproj = (const float*)d_in[8];
  const float* Wfc1  = (const float*)d_in[9];
  const float* bfc1  = (const float*)d_in[10];
  const float* Wfc2  = (const float*)d_in[11];
  const float* bfc2  = (const float*)d_in[12];
  const float* Whead = (const float*)d_in[13];
  const float* bhead = (const float*)d_in[14];
  float* out = (float*)d_out;

  char* ws = (char*)d_ws;
  size_t off = 0;
  int* idx = (int*)(ws + off);              off += (size_t)B_ * NPT * 32 * 4;   // 1.0 MB
  float* qkv = (float*)(ws + off);          off += (size_t)B_ * NPT * QKVW * 4; // 25.2 MB (also fp)
  float* fp = qkv;  // feats_proj reuses qkv region (qkv dead after attn)
  ushort_t* xbf = (ushort_t*)(ws + off);    off += (size_t)B_ * NPT * DIM_ * 2; // 4.2 MB
  ushort_t* xcat = xbf;  // xbf dead after gemm0
  ushort_t* WqkvT = (ushort_t*)(ws + off);  off += (size_t)QLEN * 2;
  ushort_t* WprojT = (ushort_t*)(ws + off); off += (size_t)PLEN * 2;
  ushort_t* WheadT = (ushort_t*)(ws + off); off += (size_t)PLEN * 2;
  float* part = (float*)(ws + off);         off += 1024 * 4;
  float* av = (float*)(ws + off);           off += 1024 * 4;

  const int M = B_ * NPT;  // 8192

  prep_kernel<<<4096, 256, 0, stream>>>(pos, x, Wqkv, Wproj, Whead,
                                        idx, xbf, WqkvT, WprojT, WheadT, part);
  gemm_rf<0><<<3072, 64, 0, stream>>>(xbf, WqkvT, nullptr, nullptr,
                                      qkv, nullptr, nullptr, QKVW);
  attn_kernel<<<dim3(M, 2), 128, 0, stream>>>(qkv, pos, idx,
                                              Wp0, bp0, Wp1, bp1, xcat);
  gemm_rf<1><<<1024, 64, 0, stream>>>(xcat, WprojT, bproj, nullptr,
                                      fp, part, nullptr, DIM_);
  msf_av_kernel<<<B_, 256, 0, stream>>>(part, Wfc1, bfc1, Wfc2, bfc2, av);
  gemm_rf<2><<<1024, 64, 0, stream>>>(xcat, WheadT, bhead, fp,
                                      out, nullptr, av, DIM_);
}